// Round 1
// baseline (234.419 us; speedup 1.0000x reference)
//
#include <hip/hip_runtime.h>
#include <hip/hip_bf16.h>

#define NB    128
#define CENC  2048
#define FIN   512
#define FHID  8
#define S2D   49
#define SO3D  455
#define HW    49

typedef unsigned short ushort_t;
typedef __bf16 bf16x8 __attribute__((ext_vector_type(8)));
typedef float  f32x4  __attribute__((ext_vector_type(4)));

// async global->LDS, 16B per lane; LDS dest = wave-uniform base + lane*16
#define GLD16(gp, lp) __builtin_amdgcn_global_load_lds( \
    (__attribute__((address_space(1))) const unsigned int*)(gp), \
    (__attribute__((address_space(3))) unsigned int*)(lp), 16, 0, 0)

__device__ __forceinline__ int soff(int l) { return l*(4*l*l-1)/3; }  // sum_{l'<l}(2l'+1)^2

__device__ __forceinline__ ushort_t f2bf(float x) {
  __hip_bfloat16 h = __float2bfloat16(x);
  return *reinterpret_cast<ushort_t*>(&h);
}
__device__ __forceinline__ float bf2f(ushort_t u) {
  __hip_bfloat16 h = *reinterpret_cast<__hip_bfloat16*>(&u);
  return __bfloat162float(h);
}

// ================= device building blocks for the fused prep kernel =================

__device__ __forceinline__ void dev_gemm_nn(float* smem,
    const float* __restrict__ A, const float* __restrict__ B, float* __restrict__ C,
    int M, int N, int K, int lda, int ldb, int ldc, float alpha, int bx, int by)
{
  float* As = smem;
  float* Bs = smem + 32*68;
  const int tid = threadIdx.x;
  const int tx = tid & 15, ty = tid >> 4;
  const int n0 = bx * 64, m0 = by * 64;
  float acc[4][4] = {};
  for (int k0 = 0; k0 < K; k0 += 32) {
    {
      const int kk = tid & 31, mmB = tid >> 5;
      #pragma unroll
      for (int j = 0; j < 8; ++j) {
        const int mm = mmB + 8*j;
        const int m = m0 + mm, k = k0 + kk;
        As[kk*68 + mm] = (m < M && k < K) ? A[(size_t)m*lda + k] : 0.f;
      }
    }
    {
      const int nn = tid & 63, kkB = tid >> 6;
      #pragma unroll
      for (int j = 0; j < 8; ++j) {
        const int kk = kkB + 4*j;
        const int n = n0 + nn, k = k0 + kk;
        Bs[kk*68 + nn] = (n < N && k < K) ? B[(size_t)k*ldb + n] : 0.f;
      }
    }
    __syncthreads();
    #pragma unroll
    for (int kk = 0; kk < 32; ++kk) {
      const float4 a4 = *(const float4*)&As[kk*68 + ty*4];
      const float4 b4 = *(const float4*)&Bs[kk*68 + tx*4];
      const float av[4] = {a4.x,a4.y,a4.z,a4.w};
      const float bv[4] = {b4.x,b4.y,b4.z,b4.w};
      #pragma unroll
      for (int i = 0; i < 4; ++i)
        #pragma unroll
        for (int j = 0; j < 4; ++j)
          acc[i][j] = fmaf(av[i], bv[j], acc[i][j]);
    }
    __syncthreads();
  }
  #pragma unroll
  for (int i = 0; i < 4; ++i) {
    const int m = m0 + ty*4 + i;
    if (m >= M) continue;
    #pragma unroll
    for (int j = 0; j < 4; ++j) {
      const int n = n0 + tx*4 + j;
      if (n >= N) continue;
      C[(size_t)m*ldc + n] = acc[i][j] * alpha;
    }
  }
}

// 64x64 transpose + fp32->bf16 cvt, packed 8B stores.
// out[c*Rp + r] = bf16(in[r*C + c]), zero-padded to (Cp, Rp). Grid covers Cp/64 x Rp/64.
__device__ __forceinline__ void dev_transpose_cvt64(float* smem,
    const float* __restrict__ in, int R, int C,
    ushort_t* __restrict__ out, int Rp, int Cp, int bx, int by)
{
  float (*t)[65] = (float(*)[65])smem;         // 64x65 fp32, <=2-way bank conflict (free)
  const int c0 = bx*64, r0 = by*64;
  const int tid = threadIdx.x;
  const int cl = tid & 63, rlB = tid >> 6;     // load: 64 consecutive c per wave-ish
  #pragma unroll
  for (int p = 0; p < 16; ++p) {
    const int rl = rlB + p*4;
    const int r = r0 + rl, c = c0 + cl;
    t[rl][cl] = (r < R && c < C) ? in[(size_t)r*C + c] : 0.f;
  }
  __syncthreads();
  // store: each thread packs 4 consecutive r into one uint2 (4x bf16, 8 B)
  #pragma unroll
  for (int p = 0; p < 4; ++p) {
    const int c = p*16 + (tid >> 4);
    const int r4 = (tid & 15) * 4;
    unsigned int lo = (unsigned int)f2bf(t[r4+0][c]) | ((unsigned int)f2bf(t[r4+1][c]) << 16);
    unsigned int hi = (unsigned int)f2bf(t[r4+2][c]) | ((unsigned int)f2bf(t[r4+3][c]) << 16);
    *(uint2*)&out[(size_t)(c0 + c)*Rp + r0 + r4] = make_uint2(lo, hi);
  }
}

// fmap transpose: 128 channels x 49 hw of one batch b; packed 8B bf16 stores.
__device__ __forceinline__ void dev_transpose_fmap(float* smem,
    const float* __restrict__ fmap, ushort_t* __restrict__ out, int cc, int b)
{
  float* Fs = smem;   // [c_local][h], 128*49 fp32 = 25088 B
  const int tid = threadIdx.x;
  const int c0 = cc*128;
  const float* fsrc = fmap + ((size_t)b*CENC + c0)*HW;   // 6272 floats contiguous, 16B aligned
  for (int idx = tid; idx < 1568; idx += 256)
    *(float4*)&Fs[idx*4] = *(const float4*)&fsrc[idx*4];
  __syncthreads();
  for (int idx = tid; idx < 1568; idx += 256) {          // 49 h * 32 groups of 4 channels
    const int h = idx >> 5, c4 = (idx & 31) * 4;
    unsigned int lo = (unsigned int)f2bf(Fs[(c4+0)*49 + h]) | ((unsigned int)f2bf(Fs[(c4+1)*49 + h]) << 16);
    unsigned int hi = (unsigned int)f2bf(Fs[(c4+2)*49 + h]) | ((unsigned int)f2bf(Fs[(c4+3)*49 + h]) << 16);
    *(uint2*)&out[(size_t)(b*49 + h)*CENC + c0 + c4] = make_uint2(lo, hi);
  }
}

__device__ __forceinline__ void dev_sumP(float* smem,
    const float* __restrict__ proj_w, const float* __restrict__ proj_Y,
    float* __restrict__ sumP)
{
  float* colsum = smem;   // 192 floats
  const int tid = threadIdx.x;
  if (tid < 192) {
    float s = 0.f;
    for (int h = 0; h < 49; ++h) s += proj_w[h*192 + tid];
    colsum[tid] = s;
  }
  __syncthreads();
  if (tid < 64) {
    float s = 0.f;
    if (tid < 49) for (int k = 0; k < 192; ++k) s += colsum[k] * proj_Y[k*49 + tid];
    sumP[tid] = (tid < 49) ? s * 0.07216878364870323f : 0.f;
  }
}

// ================= fused prep kernel =================
__global__ __launch_bounds__(256) void prep_all(
    const float* __restrict__ fmap, const float* __restrict__ conv_w,
    const float* __restrict__ proj_w, const float* __restrict__ proj_Y,
    const float* __restrict__ fs_w, const float* __restrict__ fs_Y,
    const float* __restrict__ act_to, const float* __restrict__ act_from,
    const float* __restrict__ so3_w, const float* __restrict__ so3_D,
    float* __restrict__ wP, float* __restrict__ wSumP, float* __restrict__ wPsi2,
    float* __restrict__ wPsiP,
    ushort_t* __restrict__ actToT, ushort_t* __restrict__ actFromT,
    ushort_t* __restrict__ cwT, ushort_t* __restrict__ fmapT)
{
  __shared__ float smem[6272];   // 25088 B: max(gemm 17408, cvt64 16640, fmap 25088)
  const int blk = blockIdx.x;
  const float is192 = 0.07216878364870323f;
  if (blk < 1) {
    dev_gemm_nn(smem, proj_w, proj_Y, wP, 49,49,192, 192,49,49, is192, 0, 0);
  } else if (blk < 9) {
    dev_gemm_nn(smem, so3_w, so3_D, wPsi2, 8,455,192, 192,455,455, is192, blk-1, 0);
  } else if (blk < 73) {
    dev_gemm_nn(smem, fs_w, fs_Y, wPsiP, 4096,49,192, 192,49,128, is192, 0, blk-9);
  } else if (blk < 585) {
    const int t = blk-73;   dev_transpose_cvt64(smem, act_to, 455, 4000, actToT, 512, 4096, t & 63, t >> 6);
  } else if (blk < 1097) {
    const int t = blk-585;  dev_transpose_cvt64(smem, act_from, 4000, 455, actFromT, 4096, 512, t & 7, t >> 3);
  } else if (blk < 1353) {
    const int t = blk-1097; dev_transpose_cvt64(smem, conv_w, 512, 2048, cwT, 512, 2048, t & 31, t >> 5);
  } else if (blk < 3401) {
    const int t = blk-1353; dev_transpose_fmap(smem, fmap, fmapT, t & 15, t >> 4);
  } else {
    dev_sumP(smem, proj_w, proj_Y, wSumP);
  }
}

// ============ psiT cvt + bpsi ============
__global__ __launch_bounds__(256) void psiT_bpsi(
    const float* __restrict__ wPsiP, const float* __restrict__ conv_b,
    ushort_t* __restrict__ psiT, float* __restrict__ bpsi)
{
  const int blk = blockIdx.x, tid = threadIdx.x;
  if (blk < 1024) {
    const int idx = blk*256 + tid;
    const int row = idx >> 9, f = idx & 511;
    const int g = row >> 6, ii = row & 63;
    psiT[idx] = (ii < 49) ? f2bf(wPsiP[(size_t)(f*8 + g)*128 + ii]) : (ushort_t)0;
  } else {
    const int w = tid >> 6, lane = tid & 63;
    const int gi = (blk-1024)*4 + w;
    const int g = gi >> 6, ii = gi & 63;
    float s = 0.f;
    if (ii < 49) {
      #pragma unroll
      for (int s8 = 0; s8 < 8; ++s8) {
        const int f = s8*64 + lane;
        s += conv_b[f] * bf2f(f2bf(wPsiP[(size_t)(f*8 + g)*128 + ii]));
      }
    }
    #pragma unroll
    for (int off = 32; off; off >>= 1) s += __shfl_down(s, off);
    if (lane == 0) bpsi[gi] = s;
  }
}

// ---------- bf16 MFMA NT GEMM, m97-style async staging ----------
// Tile M=64 x N=128, BK=64, 4 waves (256 thr), wave-tile 64x32 (acc[4][2]).
// Staging: global_load_lds 16B/lane direct to LDS; XOR granule swizzle
// (lane fetches global granule (lane&7)^(row&7); LDS rows contiguous 128B) keeps
// global loads coalesced AND fragment ds_read_b128 <=2-way bank-conflict (free).
// mode 0: fp32 store | mode 1: relu->bf16 | mode 2: split-K fp32 partials | mode 3: bf16
__global__ __launch_bounds__(256) void gemm4_nt(
    const ushort_t* __restrict__ A, const ushort_t* __restrict__ B, void* __restrict__ Cv,
    int M, int N, int K, int lda, int ldb, int ldc,
    int mode, int kPartLen)
{
  __shared__ ushort_t Alds[64*64];    // 8 KB : 64 rows x 64 k
  __shared__ ushort_t Blds[128*64];   // 16 KB: 128 rows x 64 k
  const int tid = threadIdx.x;
  const int wv = tid >> 6, ln = tid & 63;
  const int col = ln & 15, quad = ln >> 4;
  const int m0 = blockIdx.y * 64, n0 = blockIdx.x * 128;
  int kStart = 0, kEnd = K;
  float*    C  = (float*)Cv;
  ushort_t* Cb = (ushort_t*)Cv;
  if (mode == 2) {
    kStart = blockIdx.z * kPartLen;
    kEnd = min(K, kStart + kPartLen);
    C += (size_t)blockIdx.z * (size_t)M * (size_t)ldc;
  }

  // staging addresses (advance by 64 elements per k-iter)
  const int rl = ln >> 3;          // row within 8-row group
  const int gsw = (ln & 7) ^ rl;   // swizzled granule to FETCH (row&7 == rl)
  const ushort_t* aP[2]; const ushort_t* bP[4];
  ushort_t* aL[2]; ushort_t* bL[4];
  #pragma unroll
  for (int r = 0; r < 2; ++r) {
    const int R = wv*16 + r*8;
    aP[r] = A + (size_t)(m0 + R + rl)*lda + kStart + gsw*8;
    aL[r] = &Alds[R*64];           // wave-uniform
  }
  #pragma unroll
  for (int r = 0; r < 4; ++r) {
    const int R = wv*32 + r*8;
    bP[r] = B + (size_t)(n0 + R + rl)*ldb + kStart + gsw*8;
    bL[r] = &Blds[R*64];
  }

  f32x4 acc[4][2];
  #pragma unroll
  for (int i = 0; i < 4; ++i)
    #pragma unroll
    for (int j = 0; j < 2; ++j)
      acc[i][j] = (f32x4){0.f,0.f,0.f,0.f};

  for (int k0 = kStart; k0 < kEnd; k0 += 64) {
    #pragma unroll
    for (int r = 0; r < 2; ++r) { GLD16(aP[r], aL[r]); aP[r] += 64; }
    #pragma unroll
    for (int r = 0; r < 4; ++r) { GLD16(bP[r], bL[r]); bP[r] += 64; }
    __syncthreads();
    #pragma unroll
    for (int ks = 0; ks < 2; ++ks) {
      bf16x8 af[4], bfr[2];
      #pragma unroll
      for (int i = 0; i < 4; ++i) {
        const int row = i*16 + col;
        af[i] = *(bf16x8*)&Alds[row*64 + (((ks*4 + quad) ^ (row & 7)) << 3)];
      }
      #pragma unroll
      for (int j = 0; j < 2; ++j) {
        const int row = wv*32 + j*16 + col;
        bfr[j] = *(bf16x8*)&Blds[row*64 + (((ks*4 + quad) ^ (row & 7)) << 3)];
      }
      #pragma unroll
      for (int i = 0; i < 4; ++i)
        #pragma unroll
        for (int j = 0; j < 2; ++j)
          acc[i][j] = __builtin_amdgcn_mfma_f32_16x16x32_bf16(af[i], bfr[j], acc[i][j], 0, 0, 0);
    }
    __syncthreads();
  }

  // epilogue: C/D layout col = lane&15 (n), row = quad*4 + reg (m)
  #pragma unroll
  for (int i = 0; i < 4; ++i) {
    const int mBase = m0 + i*16 + quad*4;
    #pragma unroll
    for (int j = 0; j < 2; ++j) {
      const int n = n0 + wv*32 + j*16 + col;
      if (mode == 1) {
        #pragma unroll
        for (int r = 0; r < 4; ++r)
          Cb[(size_t)(mBase+r)*ldc + n] = f2bf(fmaxf(acc[i][j][r], 0.f));
      } else if (mode == 3) {
        #pragma unroll
        for (int r = 0; r < 4; ++r)
          Cb[(size_t)(mBase+r)*ldc + n] = f2bf(acc[i][j][r]);
      } else {
        #pragma unroll
        for (int r = 0; r < 4; ++r)
          C[(size_t)(mBase+r)*ldc + n] = acc[i][j][r];
      }
    }
  }
}

// ---------- gather_y: P-contraction + block-diag gather + rank-1 bias + 1/sqrt(512) ----------
__global__ __launch_bounds__(256) void gather_y(
    const float* __restrict__ T, const float* __restrict__ P,
    const float* __restrict__ sumP, const float* __restrict__ bpsi,
    ushort_t* __restrict__ y)
{
  __shared__ float Tg[49*64];
  __shared__ float Pl[49*49];
  __shared__ float sPl[49];
  __shared__ float bps[64];
  const int tid = threadIdx.x;
  const int g = blockIdx.x & 7, b = blockIdx.x >> 3;
  for (int idx = tid; idx < 49*64; idx += 256) {
    const int h = idx >> 6, c = idx & 63;
    Tg[idx] = T[(size_t)(b*49 + h)*512 + g*64 + c];
  }
  for (int idx = tid; idx < 2401; idx += 256) Pl[idx] = P[idx];
  if (tid < 49) sPl[tid] = sumP[tid];
  if (tid < 64) bps[tid] = bpsi[g*64 + tid];
  __syncthreads();
  #pragma unroll
  for (int rr = 0; rr < 2; ++rr) {
    const int j = tid + rr*256;
    float v = 0.f;
    if (j < SO3D) {
      int l;
      if (j < 1) l = 0; else if (j < 10) l = 1; else if (j < 35) l = 2;
      else if (j < 84) l = 3; else if (j < 165) l = 4; else if (j < 286) l = 5; else l = 6;
      const int so = soff(l), d = 2*l+1;
      const int r = j - so;
      const int u = r / d, m = r - u*d;
      const int i = l*l + m, colT = l*l + u;
      float acc = 0.f;
      #pragma unroll 7
      for (int h = 0; h < 49; ++h)
        acc = fmaf(Pl[h*49 + i], Tg[h*64 + colT], acc);
      v = (acc + sPl[i]*bps[colT]) * 0.044194173824159216f;
    }
    y[(size_t)(b*8+g)*512 + j] = f2bf(v);
  }
}

// ---------- final so3 conv: 8-partial sum + per-l contraction + fp32 store ----------
__global__ __launch_bounds__(512) void so3_final(
    const float* __restrict__ zpart, const float* __restrict__ psi2,
    float* __restrict__ out)
{
  __shared__ float Zs[8*SO3D];
  __shared__ float P2s[8*SO3D];
  const int b = blockIdx.x, tid = threadIdx.x;
  for (int idx = tid; idx < 8*SO3D; idx += 512) {
    const int f = idx / SO3D, i = idx - f*SO3D;
    float s = 0.f;
    #pragma unroll
    for (int p = 0; p < 8; ++p)
      s += zpart[((size_t)p*1024 + (size_t)b*FHID + f)*512 + i];
    Zs[idx] = s;
    P2s[idx] = psi2[idx];
  }
  __syncthreads();
  if (tid < SO3D) {
    const int i = tid;
    int l;
    if (i < 1) l = 0; else if (i < 10) l = 1; else if (i < 35) l = 2;
    else if (i < 84) l = 3; else if (i < 165) l = 4; else if (i < 286) l = 5; else l = 6;
    const int so = soff(l), d = 2*l+1;
    const int r = i - so;
    const int v = r / d, m = r - v*d;
    float acc = 0.f;
    for (int f = 0; f < 8; ++f)
      for (int u = 0; u < d; ++u)
        acc = fmaf(Zs[f*SO3D + so + u*d + m], P2s[f*SO3D + so + u*d + v], acc);
    const float scale = rsqrtf(8.0f * (float)d);
    out[(size_t)b*SO3D + i] = acc * scale;
  }
}

extern "C" void kernel_launch(void* const* d_in, const int* in_sizes, int n_in,
                              void* d_out, int out_size, void* d_ws, size_t ws_size,
                              hipStream_t stream) {
  const float* fmap    = (const float*)d_in[0];
  const float* conv_w  = (const float*)d_in[1];
  const float* conv_b  = (const float*)d_in[2];
  const float* proj_w  = (const float*)d_in[3];
  const float* proj_Y  = (const float*)d_in[4];
  const float* fs_w    = (const float*)d_in[5];
  const float* fs_Y    = (const float*)d_in[6];
  const float* act_to  = (const float*)d_in[7];
  const float* act_from= (const float*)d_in[8];
  const float* so3_w   = (const float*)d_in[9];
  const float* so3_D   = (const float*)d_in[10];
  float* out           = (float*)d_out;

  // workspace (bytes), lifetime-packed; max ~54.8 MB (known-good size)
  char* wsb = (char*)d_ws;
  float*    wP       = (float*)(wsb + 0);           // 49x49 fp32
  float*    wSumP    = (float*)(wsb + 9728);        // 64 fp32
  float*    wPsi2    = (float*)(wsb + 9984);        // 8x455 fp32 -> 24544, pad 24576
  ushort_t* actToT   = (ushort_t*)(wsb + 24576);    // 4096x512 bf16 -> 4218880
  ushort_t* actFromT = (ushort_t*)(wsb + 4218880);  // 512x4096 bf16 -> 8413184
  ushort_t* yPad     = (ushort_t*)(wsb + 8413184);  // 1024x512 bf16 -> 9461760
  ushort_t* psiT     = (ushort_t*)(wsb + 9461760);  // 512x512 bf16 -> 9986048
  float*    bpsi     = (float*)(wsb + 9986048);     // 512 fp32 -> 9988096
  ushort_t* W2T      = (ushort_t*)(wsb + 9988096);  // 512x2048 bf16 -> 12085248
  ushort_t* fmapT    = (ushort_t*)(wsb + 12085248); // 6272x2048 bf16 -> 37775360 (dead after T gemm)
  float*    wPsiP    = (float*)(wsb + 37775360);    // 4096x128 fp32 -> 39872512 (dead after psiT_bpsi)
  ushort_t* cwT      = (ushort_t*)(wsb + 39872512); // 2048x512 bf16 -> 41969664 (dead after W2T gemm)
  float*    Tbuf     = (float*)(wsb + 41969664);    // 6272x512 fp32 -> 54814720
  // aliases into dead fmapT region:
  ushort_t* gBuf     = (ushort_t*)(wsb + 12085248); // 1024x4096 bf16 -> 20473856
  float*    zPart    = (float*)(wsb + 20473856);    // 8x1024x512 fp32 -> 37251072

  // 1) ALL independent prep in one dispatch (vectorized transposes, 3402 blocks)
  prep_all<<<dim3(3402), 256, 0, stream>>>(
      fmap, conv_w, proj_w, proj_Y, fs_w, fs_Y, act_to, act_from, so3_w, so3_D,
      wP, wSumP, wPsi2, wPsiP, actToT, actFromT, cwT, fmapT);
  // 2) psiT cvt + bpsi
  psiT_bpsi<<<dim3(1152), 256, 0, stream>>>(wPsiP, conv_b, psiT, bpsi);
  // 3) W2T[gi][c] = psiT @ cwT^T   (M=512, N=2048, K=512), bf16 out
  gemm4_nt<<<dim3(16,8), 256, 0, stream>>>(psiT, cwT, W2T,
      512, 2048, 512, 512, 512, 2048, 3, 0);
  // 4) T[(b,h)][gi] = fmapT @ W2T^T  (M=6272, N=512, K=2048), fp32 out, grid 4x98
  gemm4_nt<<<dim3(4,98), 256, 0, stream>>>(fmapT, W2T, Tbuf,
      6272, 512, 2048, 2048, 2048, 512, 0, 0);
  // 5) yPad = P-contraction + block-diag gather + rank-1 bias + 1/sqrt(512)
  gather_y<<<dim3(1024), 256, 0, stream>>>(Tbuf, wP, wSumP, bpsi, yPad);
  // 6) g = relu(yPad @ actToT^T) bf16   (M=1024, N=4096, K=512)
  gemm4_nt<<<dim3(32,16), 256, 0, stream>>>(yPad, actToT, gBuf,
      1024, 4096, 512, 512, 512, 4096, 1, 0);
  // 7) zPart = gBuf @ actFromT^T, split-K=8 partial buffers  (M=1024, N=512, K=4096)
  gemm4_nt<<<dim3(4,16,8), 256, 0, stream>>>(gBuf, actFromT, zPart,
      1024, 512, 4096, 4096, 4096, 512, 2, 512);
  // 8) final contraction + fp32 store
  so3_final<<<dim3(128), 512, 0, stream>>>(zPart, wPsi2, out);
}